// Round 7
// baseline (83.218 us; speedup 1.0000x reference)
//
#include <hip/hip_runtime.h>
#include <math.h>

#define N1 16384
#define N2 16384
#define BLOCK 512                      // phase-1 block: 8 waves (R6-validated)
#define PTS 4                          // pos1 points per thread
#define I_BLOCKS (N1 / (BLOCK * PTS))  // 8 columns
#define SLICES 64                      // pos2 slices -> grid 8x64 = 512 blocks
                                       // = 2 blocks/CU x 8 waves = 4 waves/SIMD
#define KBANKS 4                       // key banks: contention 128 -> 16/addr
#define SLICE_F4 ((N2 / SLICES) / 2)   // 128 float4 per slice (512 points, 2 KB)
#define FBLOCK 256                     // finish block (proven R0 shape)

// order-preserving float<->uint mapping (for atomicMin over possibly-negative g)
__device__ __forceinline__ unsigned int f2key(float f) {
    unsigned int b = __float_as_uint(f);
    return (b & 0x80000000u) ? ~b : (b | 0x80000000u);
}
__device__ __forceinline__ float key2f(unsigned int k) {
    unsigned int b = (k & 0x80000000u) ? (k & 0x7FFFFFFFu) : ~k;
    return __uint_as_float(b);
}

// Stage 1: for each pos1 point, min over one pos2 slice of
// g(q) = -2 p.q + |q|^2  (d^2 = |p|^2 + g, shift applied in stage 2).
// R6 post-mortem: phase 1 is insensitive to instr count AND occupancy ->
// serialized shared resource. Prime suspect: the 2.1M device-scope atomicMin
// with 128-way per-address contention (per-line serialization at the
// coherent atomic point; R5's forced mid-kernel drain bounded this at
// ~5-10 us). This round: SLICES 128->64 (1.05M atomics) and 4-way key
// banking keyed by slice (contention 128 -> 16 per address). Math unchanged.
__global__ __launch_bounds__(BLOCK, 8)
void nn_partial(const float2* __restrict__ pos1,
                const float4* __restrict__ pos2,   // 2 points per float4
                unsigned int* __restrict__ keys,   // [KBANKS][N1], memset 0xFF
                unsigned int* __restrict__ ticket,
                int slice_f4) {
    const int ib = blockIdx.x;
    const int sl = blockIdx.y;
    const int t  = threadIdx.x;

    if (ib == 0 && sl == 0 && t == 0) *ticket = 0;  // init for stage 2

    const float4* __restrict__ q = pos2 + (size_t)sl * slice_f4;
    const int i0 = ib * (BLOCK * PTS) + t;

    float x[PTS], y[PTS], m[PTS];
#pragma unroll
    for (int k = 0; k < PTS; ++k) {
        float2 p = pos1[i0 + k * BLOCK];
        x[k] = -2.f * p.x;   // fold -2 into p (exact)
        y[k] = -2.f * p.y;
        m[k] = 3.4e38f;
    }

#pragma unroll 4
    for (int j = 0; j < slice_f4; ++j) {
        float4 qq = q[j];                          // uniform address, 2 pos2 pts
        float az = fmaf(qq.x, qq.x, qq.y * qq.y);  // |qa|^2
        float bz = fmaf(qq.z, qq.z, qq.w * qq.w);  // |qb|^2
#pragma unroll
        for (int k = 0; k < PTS; ++k) {
            float ta = fmaf(x[k], qq.x, fmaf(y[k], qq.y, az));
            float tb = fmaf(x[k], qq.z, fmaf(y[k], qq.w, bz));
            m[k] = fminf(m[k], fminf(ta, tb));     // -> v_min3_f32
        }
    }

    unsigned int* kb = keys + (size_t)(sl & (KBANKS - 1)) * N1;
#pragma unroll
    for (int k = 0; k < PTS; ++k) {
        atomicMin(&kb[i0 + k * BLOCK], f2key(m[k]));  // fire-and-forget
    }
}

// Stage 2 (fused final): 64 blocks; min the 4 key banks (order-preserving,
// so decode once after), + |p|^2, sqrt, block-sum; last block (ticket)
// reduces the 64 block sums and writes the mean.
__global__ __launch_bounds__(FBLOCK)
void nn_finish(const unsigned int* __restrict__ keys,
               const float2* __restrict__ pos1,
               float* __restrict__ blocksums,
               unsigned int* __restrict__ ticket,
               float* __restrict__ out) {
    const int t = threadIdx.x;
    const int i = blockIdx.x * FBLOCK + t;

    unsigned int u = keys[i];
#pragma unroll
    for (int b = 1; b < KBANKS; ++b) {
        u = min(u, keys[(size_t)b * N1 + i]);
    }
    float g = key2f(u);
    float2 p = pos1[i];
    float d2 = fmaxf(fmaf(p.x, p.x, p.y * p.y) + g, 0.f);
    float sum = sqrtf(d2);

    for (int off = 32; off > 0; off >>= 1) {
        sum += __shfl_down(sum, off, 64);
    }
    __shared__ float wsum[FBLOCK / 64];
    __shared__ int lastflag;
    if ((t & 63) == 0) wsum[t >> 6] = sum;
    __syncthreads();
    if (t == 0) {
        float s = 0.f;
        for (int w = 0; w < FBLOCK / 64; ++w) s += wsum[w];
        blocksums[blockIdx.x] = s;
        __threadfence();
        unsigned int old = atomicAdd(ticket, 1u);
        lastflag = (old == gridDim.x - 1) ? 1 : 0;
    }
    __syncthreads();
    if (lastflag && t < 64) {
        volatile float* vb = (volatile float*)blocksums;
        float v = vb[t];
        for (int off = 32; off > 0; off >>= 1) {
            v += __shfl_down(v, off, 64);
        }
        if (t == 0) out[0] = v / (float)N1;
    }
}

extern "C" void kernel_launch(void* const* d_in, const int* in_sizes, int n_in,
                              void* d_out, int out_size, void* d_ws, size_t ws_size,
                              hipStream_t stream) {
    const float2* pos1 = (const float2*)d_in[0];
    const float4* pos2 = (const float4*)d_in[1];
    float* out = (float*)d_out;

    unsigned int* keys = (unsigned int*)d_ws;               // KBANKS*N1 uints (256 KB)
    float* blocksums   = (float*)(keys + (size_t)KBANKS * N1); // 64 floats
    unsigned int* ticket = (unsigned int*)(blocksums + 64);    // 1 uint

    const int slice_f4 = SLICE_F4;

    // init all key banks to +inf ordering (0xFFFFFFFF)
    hipMemsetAsync(keys, 0xFF, (size_t)KBANKS * N1 * sizeof(unsigned int), stream);

    dim3 grid1(I_BLOCKS, SLICES);
    nn_partial<<<grid1, BLOCK, 0, stream>>>(pos1, pos2, keys, ticket, slice_f4);
    nn_finish<<<N1 / FBLOCK, FBLOCK, 0, stream>>>(keys, pos1, blocksums, ticket, out);
}